// Round 2
// baseline (222.406 us; speedup 1.0000x reference)
//
#include <hip/hip_runtime.h>
#include <stdint.h>

// NMU forward: y[b,o] = prod_d( clip(M[d,o],0,1)*x[b,d] + 1-clip(M[d,o],0,1) )
// B=16384, D=256, O=32, fp32.
//
// Round-2 structure: x is staged global->LDS with async global_load_lds
// (width 16), double-buffered over 4 chunks of 64 d's, so HBM latency is
// hidden by DMA depth instead of wave count (grid is only 2 blocks/CU).
// Compute reads x from LDS via ds_read_b128 broadcast (o-group lanes share
// the address; 2 rows per wave -> 2-way bank alias, free). M column is
// register-cached in 32-d sub-chunks from global (const offsets, L1-hot),
// amortized over R=4 rows/thread.

constexpr int D = 256;
constexpr int O = 32;
constexpr int SLOTS = 8;                // 256 threads / 32 o-lanes
constexpr int R = 4;                    // rows per thread
constexpr int ROWS = SLOTS * R;         // 32 rows per block
constexpr int DC = 64;                  // d's per staged chunk
constexpr int NCHUNK = D / DC;          // 4
constexpr int F4_PER_ROW = DC / 4;      // 16
constexpr int CHUNK_F4 = ROWS * F4_PER_ROW;  // 512 float4 per buffer

__device__ __forceinline__ void async16(const float* g, float* l) {
    __builtin_amdgcn_global_load_lds(
        (const __attribute__((address_space(1))) uint32_t*)g,
        (__attribute__((address_space(3))) uint32_t*)l, 16, 0, 0);
}

__global__ __launch_bounds__(256) void nmu_fwd(const float* __restrict__ x,
                                               const float* __restrict__ M,
                                               float* __restrict__ y)
{
    __shared__ float xb[2][ROWS * DC];     // 2 x 8 KB
    const int tid  = threadIdx.x;
    const int o    = tid & 31;
    const int slot = tid >> 5;
    const int row0 = blockIdx.x * ROWS;

    // Stage chunk k of the block's x tile into buffer b.
    // flat float4 index f = it*256+tid -> LDS byte offset 16*f = wave-uniform
    // base + lane*16, exactly the global_load_lds dest constraint (m104).
    auto stage = [&](int k, int b) {
#pragma unroll
        for (int it = 0; it < CHUNK_F4 / 256; ++it) {   // 2 issues/thread
            const int f = it * 256 + tid;
            const int r = f / F4_PER_ROW;
            const int c = f % F4_PER_ROW;
            async16(x + (row0 + r) * D + k * DC + c * 4, &xb[b][f * 4]);
        }
    };

    stage(0, 0);

    float prod[R];
#pragma unroll
    for (int i = 0; i < R; ++i) prod[i] = 1.0f;

    __syncthreads();   // compiler drains vmcnt before s_barrier -> buf0 ready

#pragma unroll
    for (int k = 0; k < NCHUNK; ++k) {
        if (k + 1 < NCHUNK) stage(k + 1, (k + 1) & 1);   // prefetch next
        const float* buf = xb[k & 1];

#pragma unroll
        for (int s = 0; s < DC / 32; ++s) {   // 32-d sub-chunks for M regs
            float mh[32], om[32];
            const int d0 = k * DC + s * 32;
#pragma unroll
            for (int j = 0; j < 32; ++j) {
                float v = M[(d0 + j) * O + o];          // const-offset, L1-hot
                v = __builtin_amdgcn_fmed3f(v, 0.0f, 1.0f);
                mh[j] = v;
                om[j] = 1.0f - v;
            }
#pragma unroll
            for (int i = 0; i < R; ++i) {
                const int r = slot + i * SLOTS;
                const float4* xp =
                    reinterpret_cast<const float4*>(buf + r * DC + s * 32);
                float p = prod[i];
#pragma unroll
                for (int q = 0; q < 8; ++q) {
                    float4 xv = xp[q];                   // ds_read_b128 bcast
                    float t0 = fmaf(xv.x, mh[4*q+0], om[4*q+0]);
                    float t1 = fmaf(xv.y, mh[4*q+1], om[4*q+1]);
                    float t2 = fmaf(xv.z, mh[4*q+2], om[4*q+2]);
                    float t3 = fmaf(xv.w, mh[4*q+3], om[4*q+3]);
                    p = p * ((t0 * t1) * (t2 * t3));     // same order as R1
                }
                prod[i] = p;
            }
        }
        __syncthreads();   // drains vmcnt: next buffer ready, this one reusable
    }

#pragma unroll
    for (int i = 0; i < R; ++i)
        y[(row0 + slot + i * SLOTS) * O + o] = prod[i];  // contiguous per row
}

extern "C" void kernel_launch(void* const* d_in, const int* in_sizes, int n_in,
                              void* d_out, int out_size, void* d_ws, size_t ws_size,
                              hipStream_t stream) {
    const float* x = (const float*)d_in[0];   // [B, 256]
    const float* M = (const float*)d_in[1];   // [256, 32]
    float* y = (float*)d_out;                 // [B, 32]
    const int B = in_sizes[0] / D;            // 16384
    dim3 grid(B / ROWS);                      // 512 blocks = 2 blocks/CU
    nmu_fwd<<<grid, 256, 0, stream>>>(x, M, y);
}